// Round 2
// baseline (3263.850 us; speedup 1.0000x reference)
//
#include <hip/hip_runtime.h>
#include <hip/hip_bf16.h>

typedef __hip_bfloat16 bf16;
typedef unsigned short ushortT;
typedef __attribute__((ext_vector_type(8))) short short8;
typedef __attribute__((ext_vector_type(4))) short s16x4;
typedef __attribute__((ext_vector_type(4))) float f32x4;

#define BB 128
#define CHAN 24
#define INNER 64
#define HW 1024
#define DD (CHAN*HW)              // 24576

constexpr size_t cBD = (size_t)BB*DD;        // 3145728 elems

// ---------------- scratch in device globals (d_ws unused) ----------------
// planar activations bf16: [b][c(24)][pix(1024)]
__device__ __attribute__((aligned(16))) ushortT g_xp[cBD];
__device__ __attribute__((aligned(16))) ushortT g_tb[cBD];    // preconv staging (chunked layout)
__device__ __attribute__((aligned(16))) ushortT g_xcur[cBD];  // current X, planar
__device__ __attribute__((aligned(16))) ushortT g_F[5*cBD];   // planar slots
__device__ __attribute__((aligned(16))) ushortT g_G[5*cBD];   // planar slots
__device__ __attribute__((aligned(16))) ushortT g_w1m[9*4*64*8]; // [s9][kchunk4][oc64][8]
__device__ __attribute__((aligned(16))) ushortT g_w2m[9*8*24*8]; // [s9][kchunk8][oc24][8]
__device__ __attribute__((aligned(16))) float g_stats2a[48];
__device__ __attribute__((aligned(16))) float g_stats2b[48];
__device__ __attribute__((aligned(16))) float g_params[5120];
__device__ unsigned g_isbf16;

#define P_PCW 0
#define P_PCB 648
#define P_PBG 672
#define P_PBB 696
#define P_G1G 720
#define P_G1B 784
#define P_G2G 848
#define P_G2B 872
#define P_G3G 896
#define P_G3B 920
#define P_POG 944
#define P_POB 968
#define P_FCW 992
#define P_FCB 4832

__device__ __forceinline__ size_t aidx(int b, int icv, int pix){
  return (((size_t)b*3 + icv)*1024 + (size_t)pix)*8;
}
__device__ __forceinline__ float rdin(const void* p, int i){
  if (g_isbf16) return __bfloat162float(((const bf16*)p)[i]);
  return ((const float*)p)[i];
}
__device__ __forceinline__ float b2f(ushortT u){
  unsigned v = ((unsigned)u) << 16;
  return __builtin_bit_cast(float, v);
}
__device__ __forceinline__ ushortT f2b(float f){
  unsigned u = __builtin_bit_cast(unsigned, f);
  u += 0x7FFFu + ((u >> 16) & 1u);   // RNE
  return (ushortT)(u >> 16);
}
__device__ __forceinline__ void ld24c(const ushortT* base, int b, int pix, float* o){
  #pragma unroll
  for (int icv=0;icv<3;icv++){
    short8 v = *(const short8*)&base[aidx(b,icv,pix)];
    #pragma unroll
    for (int j=0;j<8;j++) o[icv*8+j] = b2f((ushortT)v[j]);
  }
}
__device__ __forceinline__ void st24c(ushortT* base, int b, int pix, const float* i){
  #pragma unroll
  for (int icv=0;icv<3;icv++){
    short8 v;
    #pragma unroll
    for (int j=0;j<8;j++) v[j] = (short)f2b(i[icv*8+j]);
    *(short8*)&base[aidx(b,icv,pix)] = v;
  }
}

// ---- dtype detector ----
__global__ void detect_k(const void* g1g){
  if (threadIdx.x==0 && blockIdx.x==0){
    unsigned u = *(const unsigned*)g1g;
    g_isbf16 = (u == 0x3F803F80u) ? 1u : 0u;
  }
}

// ---- convert params to fp32; zero BN sum buffers ----
__global__ void cvt_params_k(const void* pcw, const void* pcb, const void* pbg, const void* pbb,
                             const void* g1g, const void* g1b, const void* g2g, const void* g2b,
                             const void* g3g, const void* g3b, const void* pog, const void* pob,
                             const void* fcw, const void* fcb){
  int t = threadIdx.x;
  for (int i=t;i<648;i+=256)  g_params[P_PCW+i]=rdin(pcw,i);
  for (int i=t;i<24;i+=256) { g_params[P_PCB+i]=rdin(pcb,i);
                              g_params[P_PBG+i]=rdin(pbg,i);
                              g_params[P_PBB+i]=rdin(pbb,i);
                              g_params[P_G2G+i]=rdin(g2g,i);
                              g_params[P_G2B+i]=rdin(g2b,i);
                              g_params[P_G3G+i]=rdin(g3g,i);
                              g_params[P_G3B+i]=rdin(g3b,i);
                              g_params[P_POG+i]=rdin(pog,i);
                              g_params[P_POB+i]=rdin(pob,i); }
  for (int i=t;i<64;i+=256) { g_params[P_G1G+i]=rdin(g1g,i);
                              g_params[P_G1B+i]=rdin(g1b,i); }
  for (int i=t;i<3840;i+=256) g_params[P_FCW+i]=rdin(fcw,i);
  for (int i=t;i<10;i+=256)   g_params[P_FCB+i]=rdin(fcb,i);
  for (int i=t;i<48;i+=256) { g_stats2a[i]=0.f; g_stats2b[i]=0.f; }
}

// ---- weight pack to chunk-planar bf16 MFMA layouts ----
// w1: [s9][kchunk(4)][oc(64)][8] ; w2: [s9][kchunk(8)][oc(24)][8]
__global__ void wtm_k(const void* w1, const void* w2){
  int t = blockIdx.x*256 + threadIdx.x;
  if (t < 9*4*64*8){
    int e = t & 7, oc = (t>>3)&63, chk = (t>>9)&3, s9 = t>>11;
    int ic = chk*8 + e;
    float v = (ic<24) ? rdin(w1, (oc*24+ic)*9 + s9) : 0.f;
    g_w1m[t] = f2b(v);
  }
  int u = t - 9*4*64*8;
  if (u >= 0 && u < 9*8*24*8){
    int e = u & 7; int rest = u >> 3; int oc = rest % 24; rest /= 24;
    int chk = rest & 7, s9 = rest >> 3;
    int ic = chk*8 + e;
    g_w2m[u] = f2b(rdin(w2, (oc*64+ic)*9 + s9));
  }
}

// ---- pre conv -> g_tb chunked layout + pre-BN stats (fused) ----
__global__ void preconv_k(const void* __restrict__ x){
  __shared__ float sR2d[4*48];
  int id = blockIdx.x*256 + threadIdx.x;   // pixel id 0..131071
  int b = id >> 10, pix = id & 1023;
  int yy = pix >> 5, xx = pix & 31;
  float acc[24];
  #pragma unroll
  for (int oc=0;oc<24;oc++) acc[oc] = g_params[P_PCB+oc];
  for (int ic=0; ic<3; ic++)
    for (int ky=0; ky<3; ky++){
      int gy = yy+ky-1; if (gy<0||gy>=32) continue;
      for (int kx=0;kx<3;kx++){
        int gx = xx+kx-1; if (gx<0||gx>=32) continue;
        float v = rdin(x, ((b*3+ic)*32+gy)*32+gx);
        #pragma unroll
        for (int oc=0;oc<24;oc++)
          acc[oc] += v * g_params[P_PCW+(oc*3+ic)*9+ky*3+kx];
      }
    }
  st24c(g_tb, b, pix, acc);
  int lane = threadIdx.x & 63, wv = threadIdx.x >> 6;
  #pragma unroll
  for (int c=0;c<24;c++){
    float r = acc[c], q = acc[c]*acc[c];
    #pragma unroll
    for (int off=32;off;off>>=1){ r += __shfl_down(r,off,64); q += __shfl_down(q,off,64); }
    if (lane==0){ sR2d[wv*48+c*2]=r; sR2d[wv*48+c*2+1]=q; }
  }
  __syncthreads();
  if (threadIdx.x < 48)
    atomicAdd(&g_stats2a[threadIdx.x],
      sR2d[threadIdx.x] + sR2d[48+threadIdx.x] + sR2d[96+threadIdx.x] + sR2d[144+threadIdx.x]);
}

// ---- bn apply: tb (chunked) -> xp (planar) ----
__global__ void bn_apply_k(){
  int id = blockIdx.x*256+threadIdx.x;
  int b = id >> 10, pix = id & 1023;
  const float inv = 1.f/(BB*HW);
  float tv[24];
  ld24c(g_tb, b, pix, tv);
  #pragma unroll
  for (int c=0;c<24;c++){
    float mean = g_stats2a[c*2]*inv;
    float var = fmaxf(g_stats2a[c*2+1]*inv - mean*mean, 0.f);
    float rstd = rsqrtf(var + 1e-5f);
    float ov = (tv[c]-mean)*rstd*g_params[P_PBG+c] + g_params[P_PBB+c];
    g_xp[((size_t)b*24+c)*1024 + pix] = f2b(ov);
  }
}

// ---- Cholesky solve for Anderson alpha ----
template<int N>
__device__ __forceinline__ void chol_alpha(const float Kf[5][5], float* alpha){
  double K[N][N];
  #pragma unroll
  for (int i=0;i<N;i++)
    #pragma unroll
    for (int j=0;j<N;j++)
      K[i][j] = (double)Kf[i][j] + (i==j ? 1e-4 : 0.0);
  #pragma unroll
  for (int c=0;c<N;c++){
    double d = K[c][c];
    #pragma unroll
    for (int k2=0;k2<c;k2++) d -= K[c][k2]*K[c][k2];
    d = sqrt(fmax(d, 1e-300));
    K[c][c] = d;
    double inv = 1.0/d;
    #pragma unroll
    for (int r=c+1;r<N;r++){
      double v = K[r][c];
      #pragma unroll
      for (int k2=0;k2<c;k2++) v -= K[r][k2]*K[c][k2];
      K[r][c] = v*inv;
    }
  }
  double y[N];
  #pragma unroll
  for (int i=0;i<N;i++){
    double v = 1.0;
    #pragma unroll
    for (int j=0;j<i;j++) v -= K[i][j]*y[j];
    y[i] = v / K[i][i];
  }
  double w[N];
  #pragma unroll
  for (int i=N-1;i>=0;i--){
    double v = y[i];
    #pragma unroll
    for (int j=i+1;j<N;j++) v -= K[j][i]*w[j];
    w[i] = v / K[i][i];
  }
  double sum = 0.0;
  #pragma unroll
  for (int i=0;i<N;i++) sum += w[i];
  double invs = 1.0/sum;
  #pragma unroll
  for (int i=0;i<N;i++) alpha[i] = (float)(w[i]*invs);
}

// =================== mega kernel: whole Anderson loop ===================
// grid 128 (one block per batch) x 1024 threads (16 waves).
// LDS (bytes):
//   [0,131072)        yb  [chunk8][pix1024][8] bf16   (conv2 input)
//     [0,49152)       X   [chunk3][pix1024][8] bf16   (conv1 input; alias)
//     [49152,86016)   w1  [s9][kc4][oc64][8]          (alias, restaged/iter)
//   [131072,158720)   w2  [s9][kc8][oc24][8]          (persistent)
//   [158720,161024)   float scratch (576 floats)
#define MEGA_SMEM 161024

__launch_bounds__(1024)
__global__ void mega_k(){
  extern __shared__ __align__(16) ushortT sU[];
  ushortT* sX  = sU;               // 24576 ushorts
  ushortT* sW1 = sU + 24576;       // 18432 ushorts
  ushortT* sYb = sU;               // 65536 ushorts
  ushortT* sW2 = sU + 65536;       // 13824 ushorts
  float* sS = (float*)(sU + 79360);
  float* sStat1 = sS;          // 128
  float* sAff1  = sS + 128;    // 128: sc[64], sb[64]
  float* sStat2 = sS + 256;    // 48
  float* sAff2  = sS + 304;    // 48: sc[24], sb[24]
  float* sStat3 = sS + 352;    // 16
  float* sAff3  = sS + 368;    // 48
  float* sGram  = sS + 416;    // 25 (persistent across k)
  float* sAlpha = sS + 441;    // 7
  float* sRedG  = sS + 448;    // 80 (16 waves x 5)
  float* sPost  = sS + 528;    // 48

  const int b = blockIdx.x;
  const int t = threadIdx.x;
  const int lane = t & 63, wv = t >> 6;
  const int mLane = lane & 15, q = lane >> 4;
  const int g0 = wv*4;
  const bool ntOK = (mLane < 8);
  const size_t xpb = (size_t)b*DD;

  // one-time: stage w2; zero X (LDS + planar global copy)
  for (int i=t; i<1728; i+=1024)
    *(short8*)&sW2[(size_t)i*8] = *(const short8*)&g_w2m[(size_t)i*8];
  {
    short8 z = {0,0,0,0,0,0,0,0};
    for (int i=t; i<3072; i+=1024) *(short8*)&sX[(size_t)i*8] = z;
    for (int i=t; i<3072; i+=1024) *(short8*)&g_xcur[xpb + (size_t)i*8] = z;
  }

  #pragma unroll 1
  for (int k=0; k<25; ++k){
    const int s = k % 5;
    const bool fin = (k == 24);
    const int n = fin ? 0 : ((k+1 < 5) ? (k+1) : 5);

    // stage w1 (overwritten by yb last iter) + zero stat scratch
    for (int i=t; i<2304; i+=1024)
      *(short8*)&sW1[(size_t)i*8] = *(const short8*)&g_w1m[(size_t)i*8];
    if (t < 128) sStat1[t] = 0.f;
    else if (t < 176) sStat2[t-128] = 0.f;
    else if (t < 192) sStat3[t-176] = 0.f;
    else if (t < 240) sPost[t-192] = 0.f;
    __syncthreads();   // (A) X, w1, zeros ready

    // ---------------- conv1: X -> a1 ----------------
    f32x4 a1[4][4];
    #pragma unroll
    for (int mt=0;mt<4;mt++)
      #pragma unroll
      for (int nt=0;nt<4;nt++) a1[mt][nt] = (f32x4){0.f,0.f,0.f,0.f};
    for (int s9=0; s9<9; ++s9){
      const int ky = s9/3, kx = s9 - ky*3;
      short8 bfr[4];
      #pragma unroll
      for (int nt=0;nt<4;nt++)
        bfr[nt] = *(const short8*)&sW1[(size_t)(((s9*4+q)*64) + nt*16 + mLane)*8];
      #pragma unroll
      for (int mt=0;mt<4;mt++){
        const int g = g0+mt;
        const int gy = (g>>1) + ky - 1;
        const int gx = (g&1)*16 + mLane + kx - 1;
        short8 afr = {0,0,0,0,0,0,0,0};
        if (q < 3 && gy >= 0 && gy < 32 && gx >= 0 && gx < 32)
          afr = *(const short8*)&sX[(size_t)(q*1024 + gy*32 + gx)*8];
        #pragma unroll
        for (int nt=0;nt<4;nt++)
          a1[mt][nt] = __builtin_amdgcn_mfma_f32_16x16x32_bf16(afr, bfr[nt], a1[mt][nt], 0,0,0);
      }
    }
    // rounded relu in place + GN1 stats
    #pragma unroll
    for (int nt=0;nt<4;nt++){
      float s0=0.f, s1=0.f;
      #pragma unroll
      for (int mt=0;mt<4;mt++)
        #pragma unroll
        for (int r=0;r<4;r++){
          float v = b2f(f2b(fmaxf(a1[mt][nt][r], 0.f)));
          a1[mt][nt][r] = v;
          s0 += v; s1 += v*v;
        }
      s0 += __shfl_xor(s0,16,64); s1 += __shfl_xor(s1,16,64);
      s0 += __shfl_xor(s0,32,64); s1 += __shfl_xor(s1,32,64);
      if (q == 0){
        atomicAdd(&sStat1[(nt*16+mLane)*2],   s0);
        atomicAdd(&sStat1[(nt*16+mLane)*2+1], s1);
      }
    }
    __syncthreads();   // (B) stats1 done; conv1 X-reads done
    if (t < 64){
      const int c = t, gr = c>>3;
      float S=0.f, Q=0.f;
      #pragma unroll
      for (int j2=0;j2<8;j2++){ S += sStat1[(gr*8+j2)*2]; Q += sStat1[(gr*8+j2)*2+1]; }
      float mean = S*(1.f/8192.f);
      float var  = fmaxf(Q*(1.f/8192.f) - mean*mean, 0.f);
      float rstd = rsqrtf(var + 1e-5f);
      float sc = rstd*g_params[P_G1G+c];
      sAff1[c] = sc; sAff1[64+c] = g_params[P_G1B+c] - mean*sc;
    }
    __syncthreads();   // (C) affine1 ready -> safe to overwrite X/w1 with yb
    // write yb = bf16(gn1-applied)
    #pragma unroll
    for (int nt=0;nt<4;nt++){
      const int oc = nt*16 + mLane;
      const float sc = sAff1[oc], sb = sAff1[64+oc];
      const size_t cb = (size_t)(oc>>3)*8192 + (oc&7);
      #pragma unroll
      for (int mt=0;mt<4;mt++){
        const int pb = (g0+mt)*16 + q*4;
        #pragma unroll
        for (int r=0;r<4;r++)
          sYb[cb + (size_t)(pb+r)*8] = f2b(a1[mt][nt][r]*sc + sb);
      }
    }
    __syncthreads();   // (D) yb ready

    // ---------------- conv2: yb -> a2 ----------------
    f32x4 a2[4][2];
    #pragma unroll
    for (int mt=0;mt<4;mt++){ a2[mt][0]=(f32x4){0.f,0.f,0.f,0.f}; a2[mt][1]=(f32x4){0.f,0.f,0.f,0.f}; }
    for (int s9=0; s9<9; ++s9){
      const int ky = s9/3, kx = s9 - ky*3;
      #pragma unroll
      for (int ks=0; ks<2; ++ks){
        const int ch = ks*4 + q;
        short8 b0 = *(const short8*)&sW2[(size_t)(((s9*8+ch)*24) + mLane)*8];
        short8 b1 = ntOK ? *(const short8*)&sW2[(size_t)(((s9*8+ch)*24) + 16 + mLane)*8]
                         : (short8){0,0,0,0,0,0,0,0};
        #pragma unroll
        for (int mt=0;mt<4;mt++){
          const int g = g0+mt;
          const int gy = (g>>1) + ky - 1;
          const int gx = (g&1)*16 + mLane + kx - 1;
          short8 afr = {0,0,0,0,0,0,0,0};
          if (gy>=0 && gy<32 && gx>=0 && gx<32)
            afr = *(const short8*)&sYb[(size_t)(ch*1024 + gy*32 + gx)*8];
          a2[mt][0] = __builtin_amdgcn_mfma_f32_16x16x32_bf16(afr, b0, a2[mt][0], 0,0,0);
          a2[mt][1] = __builtin_amdgcn_mfma_f32_16x16x32_bf16(afr, b1, a2[mt][1], 0,0,0);
        }
      }
    }

    // ---------------- fuse pass1: v = a2 + xp ; GN2 stats (unrounded) ----------------
    #pragma unroll
    for (int ci=0; ci<2; ++ci){
      const int c = ci*16 + mLane;
      const bool ok = (ci==0) || ntOK;
      float s0=0.f, s1=0.f;
      if (ok){
        #pragma unroll
        for (int mt=0;mt<4;mt++){
          const int p0 = (g0+mt)*16 + q*4;
          s16x4 xpv = *(const s16x4*)&g_xp[xpb + (size_t)c*1024 + p0];
          #pragma unroll
          for (int r=0;r<4;r++){
            float v = a2[mt][ci][r] + b2f((ushortT)xpv[r]);
            a2[mt][ci][r] = v;
            s0 += v; s1 += v*v;
          }
        }
      }
      s0 += __shfl_xor(s0,16,64); s1 += __shfl_xor(s1,16,64);
      s0 += __shfl_xor(s0,32,64); s1 += __shfl_xor(s1,32,64);
      if (q==0 && ok){
        atomicAdd(&sStat2[c*2],   s0);
        atomicAdd(&sStat2[c*2+1], s1);
      }
    }
    __syncthreads();  // (E) — also: all yb reads done
    if (t < 24){
      const int gr = t/3;
      float S = sStat2[(gr*3)*2]+sStat2[(gr*3+1)*2]+sStat2[(gr*3+2)*2];
      float Q = sStat2[(gr*3)*2+1]+sStat2[(gr*3+1)*2+1]+sStat2[(gr*3+2)*2+1];
      float m = S*(1.f/3072.f);
      float rstd = rsqrtf(fmaxf(Q*(1.f/3072.f)-m*m,0.f)+1e-5f);
      float sc = rstd*g_params[P_G2G+t];
      sAff2[t] = sc; sAff2[24+t] = g_params[P_G2B+t] - m*sc;
    }
    __syncthreads();  // (F)
    // pass2: val = relu(xv + round(v)*sc2+sb2) ; GN3 stats
    s16x4 xvp[2][4];
    #pragma unroll
    for (int ci=0; ci<2; ++ci){
      const int c = ci*16 + mLane;
      const bool ok = (ci==0) || ntOK;
      float s0=0.f, s1=0.f;
      if (ok){
        const float sc = sAff2[c], sb = sAff2[24+c];
        #pragma unroll
        for (int mt=0;mt<4;mt++){
          const int p0 = (g0+mt)*16 + q*4;
          xvp[ci][mt] = *(const s16x4*)&g_xcur[xpb + (size_t)c*1024 + p0];
          #pragma unroll
          for (int r=0;r<4;r++){
            float tv = b2f(f2b(a2[mt][ci][r]));
            float val = fmaxf(b2f((ushortT)xvp[ci][mt][r]) + tv*sc + sb, 0.f);
            a2[mt][ci][r] = val;
            s0 += val; s1 += val*val;
          }
        }
      }
      s0 += __shfl_xor(s0,16,64); s1 += __shfl_xor(s1,16,64);
      s0 += __shfl_xor(s0,32,64); s1 += __shfl_xor(s1,32,64);
      if (q==0 && ok){
        atomicAdd(&sStat3[(c/3)*2],   s0);
        atomicAdd(&sStat3[(c/3)*2+1], s1);
      }
    }
    __syncthreads();  // (G)
    if (t < 24){
      const int gr = t/3;
      float m = sStat3[gr*2]*(1.f/3072.f);
      float rstd = rsqrtf(fmaxf(sStat3[gr*2+1]*(1.f/3072.f)-m*m,0.f)+1e-5f);
      float sc = rstd*g_params[P_G3G+t];
      sAff3[t] = sc; sAff3[24+t] = g_params[P_G3B+t] - m*sc;
    }
    __syncthreads();  // (H)
    // pass3: fv ; store F ; gl ; store G ; gram partials
    const size_t fb = (size_t)s*cBD + xpb;
    s16x4 fvp[2][4], glp[2][4];
    #pragma unroll
    for (int ci=0; ci<2; ++ci){
      const int c = ci*16 + mLane;
      const bool ok = (ci==0) || ntOK;
      if (ok){
        const float sc = sAff3[c], sb = sAff3[24+c];
        #pragma unroll
        for (int mt=0;mt<4;mt++){
          const int p0 = (g0+mt)*16 + q*4;
          s16x4 fo, go;
          #pragma unroll
          for (int r=0;r<4;r++){
            float fv = a2[mt][ci][r]*sc + sb;
            fo[r] = (short)f2b(fv);
            go[r] = (short)f2b(fv - b2f((ushortT)xvp[ci][mt][r]));
          }
          fvp[ci][mt] = fo; glp[ci][mt] = go;
          *(s16x4*)&g_F[fb + (size_t)c*1024 + p0] = fo;
          if (!fin) *(s16x4*)&g_G[fb + (size_t)c*1024 + p0] = go;
        }
      }
    }
    if (!fin){
      float part[5];
      #pragma unroll
      for (int j=0;j<5;j++) part[j]=0.f;
      #pragma unroll
      for (int j=0;j<5;j++){
        if (j < n){
          float acc=0.f;
          #pragma unroll
          for (int ci=0; ci<2; ++ci){
            const int c = ci*16 + mLane;
            const bool ok = (ci==0) || ntOK;
            if (!ok) continue;
            #pragma unroll
            for (int mt=0;mt<4;mt++){
              if (j == s){
                #pragma unroll
                for (int r=0;r<4;r++){ float g2 = b2f((ushortT)glp[ci][mt][r]); acc += g2*g2; }
              } else {
                const int p0 = (g0+mt)*16 + q*4;
                s16x4 gj = *(const s16x4*)&g_G[(size_t)j*cBD + xpb + (size_t)c*1024 + p0];
                #pragma unroll
                for (int r=0;r<4;r++) acc += b2f((ushortT)glp[ci][mt][r])*b2f((ushortT)gj[r]);
              }
            }
          }
          part[j] = acc;
        }
      }
      #pragma unroll
      for (int j=0;j<5;j++){
        float v = part[j];
        v += __shfl_xor(v,1,64);  v += __shfl_xor(v,2,64);
        v += __shfl_xor(v,4,64);  v += __shfl_xor(v,8,64);
        v += __shfl_xor(v,16,64); v += __shfl_xor(v,32,64);
        if (lane==0) sRedG[wv*5+j] = v;
      }
      __syncthreads();  // (I)
      if (t == 0){
        for (int j=0;j<n;j++){
          float v = 0.f;
          for (int w=0;w<16;w++) v += sRedG[w*5+j];
          sGram[s*5+j] = v; sGram[j*5+s] = v;
        }
        float Kf[5][5];
        for (int i=0;i<n;i++)
          for (int j=0;j<n;j++) Kf[i][j] = sGram[i*5+j];
        float al[5];
        if (n==1) al[0]=1.f;
        else if (n==2) chol_alpha<2>(Kf, al);
        else if (n==3) chol_alpha<3>(Kf, al);
        else if (n==4) chol_alpha<4>(Kf, al);
        else chol_alpha<5>(Kf, al);
        for (int j=0;j<n;j++) sAlpha[j] = al[j];
      }
      __syncthreads();  // (J)
      float al[5];
      #pragma unroll
      for (int j=0;j<5;j++) al[j] = (j<n) ? sAlpha[j] : 0.f;
      // xnew = sum alpha_j F_j -> g_xcur (planar) + sX (LDS conv1 layout)
      #pragma unroll
      for (int ci=0; ci<2; ++ci){
        const int c = ci*16 + mLane;
        const bool ok = (ci==0) || ntOK;
        if (!ok) continue;
        const int chk = c>>3, e = c&7;
        #pragma unroll
        for (int mt=0;mt<4;mt++){
          const int p0 = (g0+mt)*16 + q*4;
          float xn[4] = {0.f,0.f,0.f,0.f};
          #pragma unroll
          for (int j=0;j<5;j++){
            if (j < n){
              if (j == s){
                #pragma unroll
                for (int r=0;r<4;r++) xn[r] += al[j]*b2f((ushortT)fvp[ci][mt][r]);
              } else {
                s16x4 fj = *(const s16x4*)&g_F[(size_t)j*cBD + xpb + (size_t)c*1024 + p0];
                #pragma unroll
                for (int r=0;r<4;r++) xn[r] += al[j]*b2f((ushortT)fj[r]);
              }
            }
          }
          s16x4 xo;
          #pragma unroll
          for (int r=0;r<4;r++) xo[r] = (short)f2b(xn[r]);
          *(s16x4*)&g_xcur[xpb + (size_t)c*1024 + p0] = xo;
          #pragma unroll
          for (int r=0;r<4;r++)
            sX[(size_t)(chk*1024 + p0 + r)*8 + e] = (ushortT)xo[r];
        }
      }
      // next-iter sync (A) orders sX writes vs conv1 reads
    } else {
      // final iter: post-BN relu stats of stored F[4]
      #pragma unroll
      for (int ci=0; ci<2; ++ci){
        const int c = ci*16 + mLane;
        const bool ok = (ci==0) || ntOK;
        float s0=0.f, s1=0.f;
        if (ok){
          #pragma unroll
          for (int mt=0;mt<4;mt++)
            #pragma unroll
            for (int r=0;r<4;r++){
              float v = fmaxf(b2f((ushortT)fvp[ci][mt][r]), 0.f);
              s0 += v; s1 += v*v;
            }
        }
        s0 += __shfl_xor(s0,16,64); s1 += __shfl_xor(s1,16,64);
        s0 += __shfl_xor(s0,32,64); s1 += __shfl_xor(s1,32,64);
        if (q==0 && ok){
          atomicAdd(&sPost[c*2],   s0);
          atomicAdd(&sPost[c*2+1], s1);
        }
      }
      __syncthreads();
      if (t < 48) atomicAdd(&g_stats2b[t], sPost[t]);
    }
  }
}

// ---- post: bn(relu(F[4])) + 8x8 avgpool + fc, one block per batch ----
__global__ void postfc_k(void* __restrict__ out){
  __shared__ float sPool[384];
  __shared__ float sMean[24], sRstd[24];
  int b = blockIdx.x, t = threadIdx.x;
  if (t < 24){
    const float inv = 1.f/(BB*HW);
    float mean = g_stats2b[t*2]*inv;
    float var = fmaxf(g_stats2b[t*2+1]*inv - mean*mean, 0.f);
    sMean[t] = mean; sRstd[t] = rsqrtf(var + 1e-5f);
  }
  __syncthreads();
  const ushortT* z = g_F + 4*cBD + (size_t)b*DD;   // planar [24][1024]
  for (int i=t; i<384; i+=256){
    int c = i>>4, bin = i&15, ph = bin>>2, pw = bin&3;
    float gg = g_params[P_POG+c], bv = g_params[P_POB+c];
    float mean = sMean[c], rstd = sRstd[c];
    float sum = 0.f;
    for (int dy=0;dy<8;dy++)
      for (int dx=0;dx<8;dx++){
        int pix = (ph*8+dy)*32 + pw*8+dx;
        float vv = fmaxf(b2f(z[(size_t)c*1024 + pix]), 0.f);
        sum += (vv-mean)*rstd*gg + bv;
      }
    sPool[i] = sum*(1.f/64.f);
  }
  __syncthreads();
  if (t < 10){
    float s2 = g_params[P_FCB+t];
    for (int k2=0;k2<384;k2++) s2 += sPool[k2]*g_params[P_FCW+t*384+k2];
    if (g_isbf16) ((bf16*)out)[b*10+t] = __float2bfloat16(s2);
    else ((float*)out)[b*10+t] = s2;
  }
}

extern "C" void kernel_launch(void* const* d_in, const int* in_sizes, int n_in,
                              void* d_out, int out_size, void* d_ws, size_t ws_size,
                              hipStream_t stream){
  const void* x   = d_in[0];
  const void* pcw = d_in[1];
  const void* pcb = d_in[2];
  const void* pbg = d_in[3];
  const void* pbb = d_in[4];
  const void* w1  = d_in[5];
  const void* g1g = d_in[6];
  const void* g1b = d_in[7];
  const void* w2  = d_in[8];
  const void* g2g = d_in[9];
  const void* g2b = d_in[10];
  const void* g3g = d_in[11];
  const void* g3b = d_in[12];
  const void* pog = d_in[13];
  const void* pob = d_in[14];
  const void* fcw = d_in[15];
  const void* fcb = d_in[16];
  (void)d_ws; (void)ws_size; (void)in_sizes; (void)n_in; (void)out_size;

  static bool attrSet = false;
  if (!attrSet){
    hipFuncSetAttribute(reinterpret_cast<const void*>(mega_k),
                        hipFuncAttributeMaxDynamicSharedMemorySize, MEGA_SMEM);
    attrSet = true;
  }

  detect_k<<<1,64,0,stream>>>(g1g);
  cvt_params_k<<<1,256,0,stream>>>(pcw,pcb,pbg,pbb,g1g,g1b,g2g,g2b,g3g,g3b,pog,pob,fcw,fcb);
  wtm_k<<<126,256,0,stream>>>(w1, w2);

  preconv_k<<<512,256,0,stream>>>(x);
  bn_apply_k<<<512,256,0,stream>>>();

  mega_k<<<128,1024,MEGA_SMEM,stream>>>();

  postfc_k<<<128,256,0,stream>>>(d_out);
}